// Round 1
// baseline (1414.328 us; speedup 1.0000x reference)
//
#include <hip/hip_runtime.h>

#define DD 2048   // hidden
#define HH 1408   // intermediate
#define EE 8      // experts
#define TT 4096   // tokens (B*S)

#define BM 128
#define BN 64
#define BK 64
#define XS 72     // LDS leading-dim padding: 64 + 8 (2-way conflict = free)

using floatx4  = __attribute__((ext_vector_type(4))) float;
using bf16x8   = __attribute__((ext_vector_type(8))) __bf16;
using ushortx8 = __attribute__((ext_vector_type(8))) unsigned short;

// round-half-up fp32->bf16 pair pack via v_perm_b32: result = (bf(b)<<16)|bf(a)
__device__ inline unsigned int pack_bf16(float a, float b) {
    unsigned int ua = __float_as_uint(a) + 0x8000u;
    unsigned int ub = __float_as_uint(b) + 0x8000u;
    return __builtin_amdgcn_perm(ub, ua, 0x07060302u);
}
__device__ inline unsigned short f2bf(float a) {
    return (unsigned short)((__float_as_uint(a) + 0x8000u) >> 16);
}

// ---------------- init: zero counts & cursors ----------------
__global__ void k_init(int* counts, int* cursor) {
    int i = threadIdx.x;
    if (i < EE) { counts[i] = 0; cursor[i] = 0; }
}

// ---------------- gate: fp32 logits, softmax, top-2 ----------------
__global__ __launch_bounds__(256) void k_gate(const float* __restrict__ x,
                                              const float* __restrict__ Wg,
                                              int* __restrict__ topk_i,
                                              float* __restrict__ topk_w,
                                              int* __restrict__ counts) {
    const int t = blockIdx.x;
    const int tid = threadIdx.x;
    float p[EE];
#pragma unroll
    for (int e = 0; e < EE; ++e) p[e] = 0.f;
    const float* xr = x + (size_t)t * DD;
    for (int d = tid; d < DD; d += 256) {
        float xv = xr[d];
#pragma unroll
        for (int e = 0; e < EE; ++e) p[e] += xv * Wg[e * DD + d];
    }
#pragma unroll
    for (int e = 0; e < EE; ++e) {
#pragma unroll
        for (int off = 32; off; off >>= 1) p[e] += __shfl_xor(p[e], off);
    }
    __shared__ float red[4][EE];
    const int wave = tid >> 6, lane = tid & 63;
    if (lane == 0) {
#pragma unroll
        for (int e = 0; e < EE; ++e) red[wave][e] = p[e];
    }
    __syncthreads();
    if (tid == 0) {
        float lg[EE];
#pragma unroll
        for (int e = 0; e < EE; ++e) lg[e] = red[0][e] + red[1][e] + red[2][e] + red[3][e];
        float mx = lg[0];
#pragma unroll
        for (int e = 1; e < EE; ++e) mx = fmaxf(mx, lg[e]);
        float den = 0.f, pr[EE];
#pragma unroll
        for (int e = 0; e < EE; ++e) { pr[e] = __expf(lg[e] - mx); den += pr[e]; }
        float inv = 1.f / den;
#pragma unroll
        for (int e = 0; e < EE; ++e) pr[e] *= inv;
        int i0 = 0; float v0 = pr[0];
#pragma unroll
        for (int e = 1; e < EE; ++e) if (pr[e] > v0) { v0 = pr[e]; i0 = e; }
        int i1 = -1; float v1 = -1.f;
#pragma unroll
        for (int e = 0; e < EE; ++e) if (e != i0 && pr[e] > v1) { v1 = pr[e]; i1 = e; }
        topk_i[t * 2 + 0] = i0; topk_i[t * 2 + 1] = i1;
        topk_w[t * 2 + 0] = v0; topk_w[t * 2 + 1] = v1;
        atomicAdd(&counts[i0], 1);
        atomicAdd(&counts[i1], 1);
    }
}

// ---------------- scan: exclusive offsets over 8 experts ----------------
__global__ void k_scan(const int* __restrict__ counts, int* __restrict__ offs) {
    if (threadIdx.x == 0) {
        int s = 0;
        for (int e = 0; e < EE; ++e) { offs[e] = s; s += counts[e]; }
    }
}

// ---------------- compact: build per-expert token lists ----------------
__global__ __launch_bounds__(256) void k_compact(const int* __restrict__ topk_i,
                                                 const float* __restrict__ topk_w,
                                                 const int* __restrict__ offs,
                                                 int* __restrict__ cursor,
                                                 int* __restrict__ tok_id,
                                                 float* __restrict__ tok_w) {
    const int t = blockIdx.x * 256 + threadIdx.x;
    if (t >= TT) return;
#pragma unroll
    for (int k = 0; k < 2; ++k) {
        int e = topk_i[t * 2 + k];
        int slot = atomicAdd(&cursor[e], 1);
        int p = offs[e] + slot;
        tok_id[p] = t;
        tok_w[p] = topk_w[t * 2 + k];
    }
}

// ---------------- residual init: out = x ----------------
__global__ __launch_bounds__(256) void k_resid(const float* __restrict__ x,
                                               float* __restrict__ out) {
    size_t i = ((size_t)blockIdx.x * 256 + threadIdx.x) * 4;
    *(float4*)(out + i) = *(const float4*)(x + i);
}

// ---------------- gemm1: h = silu(X@W1^T) * (X@W3^T), bf16 out ----------------
__global__ __launch_bounds__(256) void k_gemm1(const float* __restrict__ x,
                                               const float* __restrict__ W1,
                                               const float* __restrict__ W3,
                                               const int* __restrict__ counts,
                                               const int* __restrict__ offs,
                                               const int* __restrict__ tok_id,
                                               unsigned short* __restrict__ hbuf) {
    const int e  = blockIdx.x >> 5;
    const int m0 = (blockIdx.x & 31) * BM;
    const int cnt = counts[e];
    if (m0 >= cnt) return;
    const int n0  = blockIdx.y * BN;
    const int seg = offs[e];
    const int tid = threadIdx.x;

    __shared__ __align__(16) unsigned short Xs[BM][XS];
    __shared__ __align__(16) unsigned short W1s[BN][XS];
    __shared__ __align__(16) unsigned short W3s[BN][XS];
    __shared__ int ids[BM];

    if (tid < BM) ids[tid] = tok_id[seg + min(m0 + tid, cnt - 1)];
    __syncthreads();

    const int lane = tid & 63, wave = tid >> 6;
    const int wr = wave >> 1, wc = wave & 1;
    const int quad = lane >> 4, l16 = lane & 15;

    floatx4 acc1[4][2], acc3[4][2];
#pragma unroll
    for (int i = 0; i < 4; ++i)
#pragma unroll
        for (int j = 0; j < 2; ++j) {
            acc1[i][j] = (floatx4)(0.f);
            acc3[i][j] = (floatx4)(0.f);
        }

    const int rr = tid >> 4;          // 0..15
    const int cc = (tid & 15) * 4;    // 0..60
    const float* w1base = W1 + ((size_t)e * HH + n0) * DD;
    const float* w3base = W3 + ((size_t)e * HH + n0) * DD;

    for (int k0 = 0; k0 < DD; k0 += BK) {
        // stage X (gathered rows, fp32 -> bf16)
#pragma unroll
        for (int p = 0; p < 8; ++p) {
            int r = p * 16 + rr;
            const float4 v = *(const float4*)(x + (size_t)ids[r] * DD + k0 + cc);
            *(uint2*)&Xs[r][cc] = make_uint2(pack_bf16(v.x, v.y), pack_bf16(v.z, v.w));
        }
        // stage W1/W3 (fp32 -> bf16)
#pragma unroll
        for (int p = 0; p < 4; ++p) {
            int r = p * 16 + rr;
            const float4 v1 = *(const float4*)(w1base + (size_t)r * DD + k0 + cc);
            *(uint2*)&W1s[r][cc] = make_uint2(pack_bf16(v1.x, v1.y), pack_bf16(v1.z, v1.w));
            const float4 v3 = *(const float4*)(w3base + (size_t)r * DD + k0 + cc);
            *(uint2*)&W3s[r][cc] = make_uint2(pack_bf16(v3.x, v3.y), pack_bf16(v3.z, v3.w));
        }
        __syncthreads();
#pragma unroll
        for (int kk = 0; kk < BK; kk += 32) {
            bf16x8 a[4], b1[2], b3[2];
#pragma unroll
            for (int mf = 0; mf < 4; ++mf)
                a[mf] = *(const bf16x8*)&Xs[wr * 64 + mf * 16 + l16][kk + quad * 8];
#pragma unroll
            for (int nf = 0; nf < 2; ++nf) {
                b1[nf] = *(const bf16x8*)&W1s[wc * 32 + nf * 16 + l16][kk + quad * 8];
                b3[nf] = *(const bf16x8*)&W3s[wc * 32 + nf * 16 + l16][kk + quad * 8];
            }
#pragma unroll
            for (int mf = 0; mf < 4; ++mf)
#pragma unroll
                for (int nf = 0; nf < 2; ++nf) {
                    acc1[mf][nf] = __builtin_amdgcn_mfma_f32_16x16x32_bf16(a[mf], b1[nf], acc1[mf][nf], 0, 0, 0);
                    acc3[mf][nf] = __builtin_amdgcn_mfma_f32_16x16x32_bf16(a[mf], b3[nf], acc3[mf][nf], 0, 0, 0);
                }
        }
        __syncthreads();
    }
    // epilogue: silu(c1)*c3 -> bf16 h
#pragma unroll
    for (int mf = 0; mf < 4; ++mf) {
#pragma unroll
        for (int reg = 0; reg < 4; ++reg) {
            int m = wr * 64 + mf * 16 + quad * 4 + reg;
            if (m0 + m < cnt) {
                size_t rowoff = (size_t)(seg + m0 + m) * HH + n0 + wc * 32;
#pragma unroll
                for (int nf = 0; nf < 2; ++nf) {
                    float c1 = acc1[mf][nf][reg];
                    float c3 = acc3[mf][nf][reg];
                    float hv = (c1 / (1.f + __expf(-c1))) * c3;
                    hbuf[rowoff + nf * 16 + l16] = f2bf(hv);
                }
            }
        }
    }
}

// ---------------- gemm2: out += w * (h @ W2^T), scatter via atomics ----------------
__global__ __launch_bounds__(256) void k_gemm2(const unsigned short* __restrict__ hbuf,
                                               const float* __restrict__ W2,
                                               const int* __restrict__ counts,
                                               const int* __restrict__ offs,
                                               const int* __restrict__ tok_id,
                                               const float* __restrict__ tok_w,
                                               float* __restrict__ out) {
    const int e  = blockIdx.x >> 5;
    const int m0 = (blockIdx.x & 31) * BM;
    const int cnt = counts[e];
    if (m0 >= cnt) return;
    const int n0  = blockIdx.y * BN;   // over D
    const int seg = offs[e];
    const int tid = threadIdx.x;

    __shared__ __align__(16) unsigned short As[BM][XS];
    __shared__ __align__(16) unsigned short Bs[BN][XS];
    __shared__ int ids[BM];
    __shared__ float wts[BM];

    if (tid < BM) {
        int r = min(m0 + tid, cnt - 1);
        ids[tid] = tok_id[seg + r];
        wts[tid] = tok_w[seg + r];
    }

    const int lane = tid & 63, wave = tid >> 6;
    const int wr = wave >> 1, wc = wave & 1;
    const int quad = lane >> 4, l16 = lane & 15;

    floatx4 acc[4][2];
#pragma unroll
    for (int i = 0; i < 4; ++i)
#pragma unroll
        for (int j = 0; j < 2; ++j) acc[i][j] = (floatx4)(0.f);

    const int rr = tid >> 4;
    const int cc = (tid & 15) * 4;
    // A staging coords: 8 threads/row, 32 rows/pass
    const int ar = tid >> 3;            // 0..31
    const int ac = (tid & 7) * 8;       // 0..56
    size_t arow[4];
#pragma unroll
    for (int p = 0; p < 4; ++p)
        arow[p] = (size_t)(seg + min(m0 + p * 32 + ar, cnt - 1)) * HH;
    const float* w2base = W2 + ((size_t)e * DD + n0) * HH;

    for (int k0 = 0; k0 < HH; k0 += BK) {
        // stage A (h, bf16 direct copy)
#pragma unroll
        for (int p = 0; p < 4; ++p) {
            int r = p * 32 + ar;
            *(ushortx8*)&As[r][ac] = *(const ushortx8*)(hbuf + arow[p] + k0 + ac);
        }
        // stage B (W2 fp32 -> bf16)
#pragma unroll
        for (int p = 0; p < 4; ++p) {
            int r = p * 16 + rr;
            const float4 v = *(const float4*)(w2base + (size_t)r * HH + k0 + cc);
            *(uint2*)&Bs[r][cc] = make_uint2(pack_bf16(v.x, v.y), pack_bf16(v.z, v.w));
        }
        __syncthreads();
#pragma unroll
        for (int kk = 0; kk < BK; kk += 32) {
            bf16x8 a[4], b[2];
#pragma unroll
            for (int mf = 0; mf < 4; ++mf)
                a[mf] = *(const bf16x8*)&As[wr * 64 + mf * 16 + l16][kk + quad * 8];
#pragma unroll
            for (int nf = 0; nf < 2; ++nf)
                b[nf] = *(const bf16x8*)&Bs[wc * 32 + nf * 16 + l16][kk + quad * 8];
#pragma unroll
            for (int mf = 0; mf < 4; ++mf)
#pragma unroll
                for (int nf = 0; nf < 2; ++nf)
                    acc[mf][nf] = __builtin_amdgcn_mfma_f32_16x16x32_bf16(a[mf], b[nf], acc[mf][nf], 0, 0, 0);
        }
        __syncthreads();
    }
    // epilogue: weighted scatter-add
#pragma unroll
    for (int mf = 0; mf < 4; ++mf) {
#pragma unroll
        for (int reg = 0; reg < 4; ++reg) {
            int m = wr * 64 + mf * 16 + quad * 4 + reg;
            if (m0 + m < cnt) {
                int token = ids[m];
                float w = wts[m];
                float* orow = out + (size_t)token * DD + n0 + wc * 32;
#pragma unroll
                for (int nf = 0; nf < 2; ++nf)
                    atomicAdd(orow + nf * 16 + l16, w * acc[mf][nf][reg]);
            }
        }
    }
}

extern "C" void kernel_launch(void* const* d_in, const int* in_sizes, int n_in,
                              void* d_out, int out_size, void* d_ws, size_t ws_size,
                              hipStream_t stream) {
    const float* x  = (const float*)d_in[0];
    const float* Wg = (const float*)d_in[1];
    const float* W1 = (const float*)d_in[2];
    const float* W3 = (const float*)d_in[3];
    const float* W2 = (const float*)d_in[4];
    float* out = (float*)d_out;

    int*   counts = (int*)d_ws;
    int*   cursor = counts + 8;
    int*   offs   = cursor + 8;
    int*   topk_i = offs + 8;
    float* topk_w = (float*)(topk_i + 2 * TT);
    int*   tok_id = (int*)(topk_w + 2 * TT);
    float* tok_w  = (float*)(tok_id + 2 * TT);
    unsigned short* hbuf = (unsigned short*)(tok_w + 2 * TT);  // 2T x H bf16, ~23 MB

    k_init<<<1, 64, 0, stream>>>(counts, cursor);
    k_gate<<<TT, 256, 0, stream>>>(x, Wg, topk_i, topk_w, counts);
    k_scan<<<1, 64, 0, stream>>>(counts, offs);
    k_compact<<<TT / 256, 256, 0, stream>>>(topk_i, topk_w, offs, cursor, tok_id, tok_w);
    k_resid<<<(TT * DD / 4) / 256, 256, 0, stream>>>(x, out);
    dim3 g1(EE * (TT / BM), HH / BN);   // (256, 22)
    k_gemm1<<<g1, 256, 0, stream>>>(x, W1, W3, counts, offs, tok_id, hbuf);
    dim3 g2(EE * (TT / BM), DD / BN);   // (256, 32)
    k_gemm2<<<g2, 256, 0, stream>>>(hbuf, W2, counts, offs, tok_id, tok_w, out);
}

// Round 2
// 1183.439 us; speedup vs baseline: 1.1951x; 1.1951x over previous
//
#include <hip/hip_runtime.h>
#include <stdint.h>

#define DD 2048   // hidden
#define HH 1408   // intermediate
#define EE 8      // experts
#define TT 4096   // tokens (B*S)

#define BM 256
#define BN 64
#define BK 64

using floatx4 = __attribute__((ext_vector_type(4))) float;
using bf16x8  = __attribute__((ext_vector_type(8))) __bf16;

// round-half-up fp32->bf16 pair pack: result = (bf(b)<<16)|bf(a)
__device__ __forceinline__ unsigned int pack_bf16(float a, float b) {
    unsigned int ua = __float_as_uint(a) + 0x8000u;
    unsigned int ub = __float_as_uint(b) + 0x8000u;
    return __builtin_amdgcn_perm(ub, ua, 0x07060302u);
}
__device__ __forceinline__ unsigned short f2bf(float a) {
    return (unsigned short)((__float_as_uint(a) + 0x8000u) >> 16);
}

// async global->LDS, 16B per lane; LDS dest = base + lane*16 (wave-uniform base)
__device__ __forceinline__ void gld16(const unsigned short* g, unsigned short* l) {
    __builtin_amdgcn_global_load_lds(
        (__attribute__((address_space(1))) void*)g,
        (__attribute__((address_space(3))) void*)l, 16, 0, 0);
}

// ---------------- fp32 -> bf16 bulk convert (8 elems/thread) ----------------
__global__ __launch_bounds__(256) void k_cvt(const float* __restrict__ src,
                                             unsigned short* __restrict__ dst, int n8) {
    int i = blockIdx.x * 256 + threadIdx.x;
    if (i >= n8) return;
    const float4* s = (const float4*)src + (size_t)i * 2;
    float4 a = s[0], b = s[1];
    uint4 o;
    o.x = pack_bf16(a.x, a.y); o.y = pack_bf16(a.z, a.w);
    o.z = pack_bf16(b.x, b.y); o.w = pack_bf16(b.z, b.w);
    *(uint4*)(dst + (size_t)i * 8) = o;
}

// ---------------- init: zero counts & cursors ----------------
__global__ void k_init(int* counts, int* cursor) {
    int i = threadIdx.x;
    if (i < EE) { counts[i] = 0; cursor[i] = 0; }
}

// ---------------- gate: fp32 logits, softmax, top-2 ----------------
__global__ __launch_bounds__(256) void k_gate(const float* __restrict__ x,
                                              const float* __restrict__ Wg,
                                              int* __restrict__ topk_i,
                                              float* __restrict__ topk_w,
                                              int* __restrict__ counts) {
    const int t = blockIdx.x;
    const int tid = threadIdx.x;
    float p[EE];
#pragma unroll
    for (int e = 0; e < EE; ++e) p[e] = 0.f;
    const float* xr = x + (size_t)t * DD;
    for (int d = tid; d < DD; d += 256) {
        float xv = xr[d];
#pragma unroll
        for (int e = 0; e < EE; ++e) p[e] += xv * Wg[e * DD + d];
    }
#pragma unroll
    for (int e = 0; e < EE; ++e) {
#pragma unroll
        for (int off = 32; off; off >>= 1) p[e] += __shfl_xor(p[e], off);
    }
    __shared__ float red[4][EE];
    const int wave = tid >> 6, lane = tid & 63;
    if (lane == 0) {
#pragma unroll
        for (int e = 0; e < EE; ++e) red[wave][e] = p[e];
    }
    __syncthreads();
    if (tid == 0) {
        float lg[EE];
#pragma unroll
        for (int e = 0; e < EE; ++e) lg[e] = red[0][e] + red[1][e] + red[2][e] + red[3][e];
        float mx = lg[0];
#pragma unroll
        for (int e = 1; e < EE; ++e) mx = fmaxf(mx, lg[e]);
        float den = 0.f, pr[EE];
#pragma unroll
        for (int e = 0; e < EE; ++e) { pr[e] = __expf(lg[e] - mx); den += pr[e]; }
        float inv = 1.f / den;
#pragma unroll
        for (int e = 0; e < EE; ++e) pr[e] *= inv;
        int i0 = 0; float v0 = pr[0];
#pragma unroll
        for (int e = 1; e < EE; ++e) if (pr[e] > v0) { v0 = pr[e]; i0 = e; }
        int i1 = -1; float v1 = -1.f;
#pragma unroll
        for (int e = 0; e < EE; ++e) if (e != i0 && pr[e] > v1) { v1 = pr[e]; i1 = e; }
        topk_i[t * 2 + 0] = i0; topk_i[t * 2 + 1] = i1;
        topk_w[t * 2 + 0] = v0; topk_w[t * 2 + 1] = v1;
        atomicAdd(&counts[i0], 1);
        atomicAdd(&counts[i1], 1);
    }
}

// ---------------- scan ----------------
__global__ void k_scan(const int* __restrict__ counts, int* __restrict__ offs) {
    if (threadIdx.x == 0) {
        int s = 0;
        for (int e = 0; e < EE; ++e) { offs[e] = s; s += counts[e]; }
    }
}

// ---------------- compact ----------------
__global__ __launch_bounds__(256) void k_compact(const int* __restrict__ topk_i,
                                                 const float* __restrict__ topk_w,
                                                 const int* __restrict__ offs,
                                                 int* __restrict__ cursor,
                                                 int* __restrict__ tok_id,
                                                 float* __restrict__ tok_w) {
    const int t = blockIdx.x * 256 + threadIdx.x;
    if (t >= TT) return;
#pragma unroll
    for (int k = 0; k < 2; ++k) {
        int e = topk_i[t * 2 + k];
        int slot = atomicAdd(&cursor[e], 1);
        int p = offs[e] + slot;
        tok_id[p] = t;
        tok_w[p] = topk_w[t * 2 + k];
    }
}

// ---------------- residual init: out = x ----------------
__global__ __launch_bounds__(256) void k_resid(const float* __restrict__ x,
                                               float* __restrict__ out) {
    size_t i = ((size_t)blockIdx.x * 256 + threadIdx.x) * 4;
    *(float4*)(out + i) = *(const float4*)(x + i);
}

// ---------------- gemm1: h = silu(X@W1^T) * (X@W3^T) ----------------
// 256x64 tile, bf16 inputs, global_load_lds staging w/ XOR-swizzled LDS.
__global__ __launch_bounds__(256, 2) void k_gemm1(const unsigned short* __restrict__ Xb,
                                                  const unsigned short* __restrict__ W1b,
                                                  const unsigned short* __restrict__ W3b,
                                                  const int* __restrict__ counts,
                                                  const int* __restrict__ offs,
                                                  const int* __restrict__ tok_id,
                                                  unsigned short* __restrict__ hbuf) {
    const int e  = blockIdx.x >> 4;
    const int m0 = (blockIdx.x & 15) * BM;
    const int cnt = counts[e];
    if (m0 >= cnt) return;
    const int n0  = blockIdx.y * BN;
    const int seg = offs[e];
    const int tid = threadIdx.x;

    __shared__ __align__(16) unsigned short Xs[BM * 64];   // 32 KB, swizzled rows
    __shared__ __align__(16) unsigned short W1s[BN * 64];  // 8 KB
    __shared__ __align__(16) unsigned short W3s[BN * 64];  // 8 KB
    __shared__ int ids[BM];

    ids[tid] = tok_id[seg + min(m0 + tid, cnt - 1)];
    __syncthreads();

    const int lane = tid & 63, wave = tid >> 6;
    const int lr = lane >> 3, lc = lane & 7;       // staging: row-in-8, chunk slot
    const int quad = lane >> 4, l16 = lane & 15;

    // per-lane global pointers (swizzle applied on the global side)
    const unsigned short* xp[8];
#pragma unroll
    for (int j = 0; j < 8; ++j) {
        int rl = wave * 64 + j * 8 + lr;
        xp[j] = Xb + (size_t)ids[rl] * DD + (lc ^ (rl & 7)) * 8;
    }
    const unsigned short* w1p[2];
    const unsigned short* w3p[2];
#pragma unroll
    for (int j = 0; j < 2; ++j) {
        int rl = wave * 16 + j * 8 + lr;
        size_t ro = ((size_t)e * HH + n0 + rl) * DD + (lc ^ (rl & 7)) * 8;
        w1p[j] = W1b + ro;
        w3p[j] = W3b + ro;
    }

    floatx4 acc1[4][4], acc3[4][4];
#pragma unroll
    for (int i = 0; i < 4; ++i)
#pragma unroll
        for (int j = 0; j < 4; ++j) { acc1[i][j] = (floatx4)(0.f); acc3[i][j] = (floatx4)(0.f); }

    for (int k0 = 0; k0 < DD; k0 += BK) {
#pragma unroll
        for (int j = 0; j < 8; ++j)
            gld16(xp[j] + k0, &Xs[(wave * 64 + j * 8) * 64]);
#pragma unroll
        for (int j = 0; j < 2; ++j) {
            gld16(w1p[j] + k0, &W1s[(wave * 16 + j * 8) * 64]);
            gld16(w3p[j] + k0, &W3s[(wave * 16 + j * 8) * 64]);
        }
        __syncthreads();
#pragma unroll
        for (int kk = 0; kk < 2; ++kk) {
            bf16x8 a[4], b1[4], b3[4];
#pragma unroll
            for (int mf = 0; mf < 4; ++mf) {
                int r = wave * 64 + mf * 16 + l16;
                int s = (quad + kk * 4) ^ (r & 7);
                a[mf] = *(const bf16x8*)&Xs[r * 64 + s * 8];
            }
#pragma unroll
            for (int nf = 0; nf < 4; ++nf) {
                int r = nf * 16 + l16;
                int s = (quad + kk * 4) ^ (r & 7);
                b1[nf] = *(const bf16x8*)&W1s[r * 64 + s * 8];
                b3[nf] = *(const bf16x8*)&W3s[r * 64 + s * 8];
            }
#pragma unroll
            for (int mf = 0; mf < 4; ++mf)
#pragma unroll
                for (int nf = 0; nf < 4; ++nf) {
                    acc1[mf][nf] = __builtin_amdgcn_mfma_f32_16x16x32_bf16(a[mf], b1[nf], acc1[mf][nf], 0, 0, 0);
                    acc3[mf][nf] = __builtin_amdgcn_mfma_f32_16x16x32_bf16(a[mf], b3[nf], acc3[mf][nf], 0, 0, 0);
                }
        }
        __syncthreads();
    }
#pragma unroll
    for (int mf = 0; mf < 4; ++mf)
#pragma unroll
        for (int reg = 0; reg < 4; ++reg) {
            int m = wave * 64 + mf * 16 + quad * 4 + reg;
            if (m0 + m < cnt) {
                size_t row = (size_t)(seg + m0 + m) * HH + n0;
#pragma unroll
                for (int nf = 0; nf < 4; ++nf) {
                    float c1 = acc1[mf][nf][reg];
                    float c3 = acc3[mf][nf][reg];
                    float hv = (c1 / (1.f + __expf(-c1))) * c3;
                    hbuf[row + nf * 16 + l16] = f2bf(hv);
                }
            }
        }
}

// ---------------- gemm2: out += w * (h @ W2^T) ----------------
__global__ __launch_bounds__(256, 2) void k_gemm2(const unsigned short* __restrict__ hbuf,
                                                  const unsigned short* __restrict__ W2b,
                                                  const int* __restrict__ counts,
                                                  const int* __restrict__ offs,
                                                  const int* __restrict__ tok_id,
                                                  const float* __restrict__ tok_w,
                                                  float* __restrict__ out) {
    const int e  = blockIdx.x >> 4;
    const int m0 = (blockIdx.x & 15) * BM;
    const int cnt = counts[e];
    if (m0 >= cnt) return;
    const int n0  = blockIdx.y * BN;   // over D
    const int seg = offs[e];
    const int tid = threadIdx.x;

    __shared__ __align__(16) unsigned short As[BM * 64];   // 32 KB
    __shared__ __align__(16) unsigned short Bs[BN * 64];   // 8 KB
    __shared__ int ids[BM];
    __shared__ float wts[BM];

    {
        int rc = min(m0 + tid, cnt - 1);
        ids[tid] = tok_id[seg + rc];
        wts[tid] = tok_w[seg + rc];
    }

    const int lane = tid & 63, wave = tid >> 6;
    const int lr = lane >> 3, lc = lane & 7;
    const int quad = lane >> 4, l16 = lane & 15;

    const unsigned short* ap[8];
#pragma unroll
    for (int j = 0; j < 8; ++j) {
        int rl = wave * 64 + j * 8 + lr;
        ap[j] = hbuf + (size_t)(seg + min(m0 + rl, cnt - 1)) * HH + (lc ^ (rl & 7)) * 8;
    }
    const unsigned short* bp[2];
#pragma unroll
    for (int j = 0; j < 2; ++j) {
        int rl = wave * 16 + j * 8 + lr;
        bp[j] = W2b + ((size_t)e * DD + n0 + rl) * HH + (lc ^ (rl & 7)) * 8;
    }

    floatx4 acc[4][4];
#pragma unroll
    for (int i = 0; i < 4; ++i)
#pragma unroll
        for (int j = 0; j < 4; ++j) acc[i][j] = (floatx4)(0.f);

    for (int k0 = 0; k0 < HH; k0 += BK) {
#pragma unroll
        for (int j = 0; j < 8; ++j)
            gld16(ap[j] + k0, &As[(wave * 64 + j * 8) * 64]);
#pragma unroll
        for (int j = 0; j < 2; ++j)
            gld16(bp[j] + k0, &Bs[(wave * 16 + j * 8) * 64]);
        __syncthreads();
#pragma unroll
        for (int kk = 0; kk < 2; ++kk) {
            bf16x8 a[4], b[4];
#pragma unroll
            for (int mf = 0; mf < 4; ++mf) {
                int r = wave * 64 + mf * 16 + l16;
                int s = (quad + kk * 4) ^ (r & 7);
                a[mf] = *(const bf16x8*)&As[r * 64 + s * 8];
            }
#pragma unroll
            for (int nf = 0; nf < 4; ++nf) {
                int r = nf * 16 + l16;
                int s = (quad + kk * 4) ^ (r & 7);
                b[nf] = *(const bf16x8*)&Bs[r * 64 + s * 8];
            }
#pragma unroll
            for (int mf = 0; mf < 4; ++mf)
#pragma unroll
                for (int nf = 0; nf < 4; ++nf)
                    acc[mf][nf] = __builtin_amdgcn_mfma_f32_16x16x32_bf16(a[mf], b[nf], acc[mf][nf], 0, 0, 0);
        }
        __syncthreads();
    }
#pragma unroll
    for (int mf = 0; mf < 4; ++mf)
#pragma unroll
        for (int reg = 0; reg < 4; ++reg) {
            int m = wave * 64 + mf * 16 + quad * 4 + reg;
            if (m0 + m < cnt) {
                int token = ids[m];
                float w = wts[m];
                float* orow = out + (size_t)token * DD + n0;
#pragma unroll
                for (int nf = 0; nf < 4; ++nf)
                    atomicAdd(orow + nf * 16 + l16, w * acc[mf][nf][reg]);
            }
        }
}

extern "C" void kernel_launch(void* const* d_in, const int* in_sizes, int n_in,
                              void* d_out, int out_size, void* d_ws, size_t ws_size,
                              hipStream_t stream) {
    const float* x  = (const float*)d_in[0];
    const float* Wg = (const float*)d_in[1];
    const float* W1 = (const float*)d_in[2];
    const float* W3 = (const float*)d_in[3];
    const float* W2 = (const float*)d_in[4];
    float* out = (float*)d_out;

    int*   counts = (int*)d_ws;
    int*   cursor = counts + 8;
    int*   offs   = cursor + 8;
    int*   topk_i = offs + 8;
    float* topk_w = (float*)(topk_i + 2 * TT);
    int*   tok_id = (int*)(topk_w + 2 * TT);
    float* tok_w  = (float*)(tok_id + 2 * TT);
    unsigned short* hbuf = (unsigned short*)(tok_w + 2 * TT);     // 2T x H bf16
    unsigned short* Xb   = hbuf + (size_t)2 * TT * HH;            // T x D bf16
    unsigned short* W1b  = Xb + (size_t)TT * DD;                  // E x H x D bf16
    unsigned short* W3b  = W1b + (size_t)EE * HH * DD;
    unsigned short* W2b  = W3b + (size_t)EE * HH * DD;            // E x D x H bf16
    // total ws use ~178.4 MB

    const int nW8 = EE * HH * DD / 8;   // 2883584
    const int nX8 = TT * DD / 8;        // 1048576

    k_init<<<1, 64, 0, stream>>>(counts, cursor);
    k_cvt<<<(nX8 + 255) / 256, 256, 0, stream>>>(x, Xb, nX8);
    k_cvt<<<(nW8 + 255) / 256, 256, 0, stream>>>(W1, W1b, nW8);
    k_cvt<<<(nW8 + 255) / 256, 256, 0, stream>>>(W3, W3b, nW8);
    k_cvt<<<(nW8 + 255) / 256, 256, 0, stream>>>(W2, W2b, nW8);
    k_gate<<<TT, 256, 0, stream>>>(x, Wg, topk_i, topk_w, counts);
    k_scan<<<1, 64, 0, stream>>>(counts, offs);
    k_compact<<<TT / 256, 256, 0, stream>>>(topk_i, topk_w, offs, cursor, tok_id, tok_w);
    k_resid<<<(TT * DD / 4) / 256, 256, 0, stream>>>(x, out);
    dim3 g1(EE * (TT / BM), HH / BN);   // (128, 22)
    k_gemm1<<<g1, 256, 0, stream>>>(Xb, W1b, W3b, counts, offs, tok_id, hbuf);
    dim3 g2(EE * (TT / BM), DD / BN);   // (128, 32)
    k_gemm2<<<g2, 256, 0, stream>>>(hbuf, W2b, counts, offs, tok_id, tok_w, out);
}

// Round 3
// 699.822 us; speedup vs baseline: 2.0210x; 1.6911x over previous
//
#include <hip/hip_runtime.h>
#include <stdint.h>

#define DD 2048   // hidden
#define HH 1408   // intermediate
#define EE 8      // experts
#define TT 4096   // tokens (B*S)

#define BM 256
#define BN 64
#define BK 64
#define MAXBLK 48   // >= max live m-blocks = 32 + 7 rounding
#define NB1 22      // HH / BN
#define NB2 32      // DD / BN

using floatx4 = __attribute__((ext_vector_type(4))) float;
using bf16x8  = __attribute__((ext_vector_type(8))) __bf16;

// round-half-up fp32->bf16 pair pack: result = (bf(b)<<16)|bf(a)
__device__ __forceinline__ unsigned int pack_bf16(float a, float b) {
    unsigned int ua = __float_as_uint(a) + 0x8000u;
    unsigned int ub = __float_as_uint(b) + 0x8000u;
    return __builtin_amdgcn_perm(ub, ua, 0x07060302u);
}
__device__ __forceinline__ unsigned short f2bf(float a) {
    return (unsigned short)((__float_as_uint(a) + 0x8000u) >> 16);
}

// async global->LDS, 16B per lane; LDS dest = base + lane*16 (wave-uniform base)
__device__ __forceinline__ void gld16(const unsigned short* g, unsigned short* l) {
    __builtin_amdgcn_global_load_lds(
        (__attribute__((address_space(1))) void*)g,
        (__attribute__((address_space(3))) void*)l, 16, 0, 0);
}

// ---------------- fp32 -> bf16 bulk convert (8 elems/thread) ----------------
__global__ __launch_bounds__(256) void k_cvt(const float* __restrict__ src,
                                             unsigned short* __restrict__ dst, int n8) {
    int i = blockIdx.x * 256 + threadIdx.x;
    if (i >= n8) return;
    const float4* s = (const float4*)src + (size_t)i * 2;
    float4 a = s[0], b = s[1];
    uint4 o;
    o.x = pack_bf16(a.x, a.y); o.y = pack_bf16(a.z, a.w);
    o.z = pack_bf16(b.x, b.y); o.w = pack_bf16(b.z, b.w);
    *(uint4*)(dst + (size_t)i * 8) = o;
}

// ---------------- init: zero counts & cursors ----------------
__global__ void k_init(int* counts, int* cursor) {
    int i = threadIdx.x;
    if (i < EE) { counts[i] = 0; cursor[i] = 0; }
}

// ---------------- gate: fp32 logits, softmax, top-2 ----------------
__global__ __launch_bounds__(256) void k_gate(const float* __restrict__ x,
                                              const float* __restrict__ Wg,
                                              int* __restrict__ topk_i,
                                              float* __restrict__ topk_w,
                                              int* __restrict__ counts) {
    const int t = blockIdx.x;
    const int tid = threadIdx.x;
    float p[EE];
#pragma unroll
    for (int e = 0; e < EE; ++e) p[e] = 0.f;
    const float* xr = x + (size_t)t * DD;
    for (int d = tid; d < DD; d += 256) {
        float xv = xr[d];
#pragma unroll
        for (int e = 0; e < EE; ++e) p[e] += xv * Wg[e * DD + d];
    }
#pragma unroll
    for (int e = 0; e < EE; ++e) {
#pragma unroll
        for (int off = 32; off; off >>= 1) p[e] += __shfl_xor(p[e], off);
    }
    __shared__ float red[4][EE];
    const int wave = tid >> 6, lane = tid & 63;
    if (lane == 0) {
#pragma unroll
        for (int e = 0; e < EE; ++e) red[wave][e] = p[e];
    }
    __syncthreads();
    if (tid == 0) {
        float lg[EE];
#pragma unroll
        for (int e = 0; e < EE; ++e) lg[e] = red[0][e] + red[1][e] + red[2][e] + red[3][e];
        float mx = lg[0];
#pragma unroll
        for (int e = 1; e < EE; ++e) mx = fmaxf(mx, lg[e]);
        float den = 0.f, pr[EE];
#pragma unroll
        for (int e = 0; e < EE; ++e) { pr[e] = __expf(lg[e] - mx); den += pr[e]; }
        float inv = 1.f / den;
#pragma unroll
        for (int e = 0; e < EE; ++e) pr[e] *= inv;
        int i0 = 0; float v0 = pr[0];
#pragma unroll
        for (int e = 1; e < EE; ++e) if (pr[e] > v0) { v0 = pr[e]; i0 = e; }
        int i1 = -1; float v1 = -1.f;
#pragma unroll
        for (int e = 0; e < EE; ++e) if (e != i0 && pr[e] > v1) { v1 = pr[e]; i1 = e; }
        topk_i[t * 2 + 0] = i0; topk_i[t * 2 + 1] = i1;
        topk_w[t * 2 + 0] = v0; topk_w[t * 2 + 1] = v1;
        atomicAdd(&counts[i0], 1);
        atomicAdd(&counts[i1], 1);
    }
}

// ---------------- scan + live-block table ----------------
__global__ void k_scan(const int* __restrict__ counts, int* __restrict__ offs,
                       int* __restrict__ blk_e, int* __restrict__ blk_m,
                       int* __restrict__ nblk) {
    if (threadIdx.x == 0) {
        int s = 0, nb = 0;
        for (int e = 0; e < EE; ++e) {
            offs[e] = s;
            int c = counts[e];
            for (int m = 0; m < c; m += BM) { blk_e[nb] = e; blk_m[nb] = m; ++nb; }
            s += c;
        }
        *nblk = nb;
        for (int i = nb; i < MAXBLK; ++i) { blk_e[i] = 0; blk_m[i] = 0; }
    }
}

// ---------------- compact ----------------
__global__ __launch_bounds__(256) void k_compact(const int* __restrict__ topk_i,
                                                 const float* __restrict__ topk_w,
                                                 const int* __restrict__ offs,
                                                 int* __restrict__ cursor,
                                                 int* __restrict__ tok_id,
                                                 float* __restrict__ tok_w) {
    const int t = blockIdx.x * 256 + threadIdx.x;
    if (t >= TT) return;
#pragma unroll
    for (int k = 0; k < 2; ++k) {
        int e = topk_i[t * 2 + k];
        int slot = atomicAdd(&cursor[e], 1);
        int p = offs[e] + slot;
        tok_id[p] = t;
        tok_w[p] = topk_w[t * 2 + k];
    }
}

// ---------------- residual init: out = x ----------------
__global__ __launch_bounds__(256) void k_resid(const float* __restrict__ x,
                                               float* __restrict__ out) {
    size_t i = ((size_t)blockIdx.x * 256 + threadIdx.x) * 4;
    *(float4*)(out + i) = *(const float4*)(x + i);
}

// ---------------- gemm1: h = silu(X@W1^T) * (X@W3^T) ----------------
// dense live-block 1D grid: bid = b * NB1 + n  (dead blocks = contiguous tail)
__global__ __launch_bounds__(256, 2) void k_gemm1(const unsigned short* __restrict__ Xb,
                                                  const unsigned short* __restrict__ W1b,
                                                  const unsigned short* __restrict__ W3b,
                                                  const int* __restrict__ counts,
                                                  const int* __restrict__ offs,
                                                  const int* __restrict__ blk_e,
                                                  const int* __restrict__ blk_m,
                                                  const int* __restrict__ nblk,
                                                  const int* __restrict__ tok_id,
                                                  unsigned short* __restrict__ hbuf) {
    const int b = blockIdx.x / NB1;
    if (b >= *nblk) return;
    const int e  = blk_e[b];
    const int m0 = blk_m[b];
    const int cnt = counts[e];
    const int n0  = (blockIdx.x % NB1) * BN;
    const int seg = offs[e];
    const int tid = threadIdx.x;

    __shared__ __align__(16) unsigned short Xs[BM * 64];   // 32 KB, swizzled rows
    __shared__ __align__(16) unsigned short W1s[BN * 64];  // 8 KB
    __shared__ __align__(16) unsigned short W3s[BN * 64];  // 8 KB
    __shared__ int ids[BM];

    ids[tid] = tok_id[seg + min(m0 + tid, cnt - 1)];
    __syncthreads();

    const int lane = tid & 63, wave = tid >> 6;
    const int lr = lane >> 3, lc = lane & 7;       // staging: row-in-8, chunk slot
    const int quad = lane >> 4, l16 = lane & 15;

    // per-lane global pointers (swizzle applied on the global side)
    const unsigned short* xp[8];
#pragma unroll
    for (int j = 0; j < 8; ++j) {
        int rl = wave * 64 + j * 8 + lr;
        xp[j] = Xb + (size_t)ids[rl] * DD + (lc ^ (rl & 7)) * 8;
    }
    const unsigned short* w1p[2];
    const unsigned short* w3p[2];
#pragma unroll
    for (int j = 0; j < 2; ++j) {
        int rl = wave * 16 + j * 8 + lr;
        size_t ro = ((size_t)e * HH + n0 + rl) * DD + (lc ^ (rl & 7)) * 8;
        w1p[j] = W1b + ro;
        w3p[j] = W3b + ro;
    }

    floatx4 acc1[4][4], acc3[4][4];
#pragma unroll
    for (int i = 0; i < 4; ++i)
#pragma unroll
        for (int j = 0; j < 4; ++j) { acc1[i][j] = (floatx4)(0.f); acc3[i][j] = (floatx4)(0.f); }

    for (int k0 = 0; k0 < DD; k0 += BK) {
#pragma unroll
        for (int j = 0; j < 8; ++j)
            gld16(xp[j] + k0, &Xs[(wave * 64 + j * 8) * 64]);
#pragma unroll
        for (int j = 0; j < 2; ++j) {
            gld16(w1p[j] + k0, &W1s[(wave * 16 + j * 8) * 64]);
            gld16(w3p[j] + k0, &W3s[(wave * 16 + j * 8) * 64]);
        }
        __syncthreads();
#pragma unroll
        for (int kk = 0; kk < 2; ++kk) {
            bf16x8 a[4], b1[4], b3[4];
#pragma unroll
            for (int mf = 0; mf < 4; ++mf) {
                int r = wave * 64 + mf * 16 + l16;
                int s = (quad + kk * 4) ^ (r & 7);
                a[mf] = *(const bf16x8*)&Xs[r * 64 + s * 8];
            }
#pragma unroll
            for (int nf = 0; nf < 4; ++nf) {
                int r = nf * 16 + l16;
                int s = (quad + kk * 4) ^ (r & 7);
                b1[nf] = *(const bf16x8*)&W1s[r * 64 + s * 8];
                b3[nf] = *(const bf16x8*)&W3s[r * 64 + s * 8];
            }
#pragma unroll
            for (int mf = 0; mf < 4; ++mf)
#pragma unroll
                for (int nf = 0; nf < 4; ++nf) {
                    acc1[mf][nf] = __builtin_amdgcn_mfma_f32_16x16x32_bf16(a[mf], b1[nf], acc1[mf][nf], 0, 0, 0);
                    acc3[mf][nf] = __builtin_amdgcn_mfma_f32_16x16x32_bf16(a[mf], b3[nf], acc3[mf][nf], 0, 0, 0);
                }
        }
        __syncthreads();
    }
#pragma unroll
    for (int mf = 0; mf < 4; ++mf)
#pragma unroll
        for (int reg = 0; reg < 4; ++reg) {
            int m = wave * 64 + mf * 16 + quad * 4 + reg;
            if (m0 + m < cnt) {
                size_t row = (size_t)(seg + m0 + m) * HH + n0;
#pragma unroll
                for (int nf = 0; nf < 4; ++nf) {
                    float c1 = acc1[mf][nf][reg];
                    float c3 = acc3[mf][nf][reg];
                    float hv = (c1 / (1.f + __expf(-c1))) * c3;
                    hbuf[row + nf * 16 + l16] = f2bf(hv);
                }
            }
        }
}

// ---------------- gemm2: out += w * (h @ W2^T) ----------------
__global__ __launch_bounds__(256, 2) void k_gemm2(const unsigned short* __restrict__ hbuf,
                                                  const unsigned short* __restrict__ W2b,
                                                  const int* __restrict__ counts,
                                                  const int* __restrict__ offs,
                                                  const int* __restrict__ blk_e,
                                                  const int* __restrict__ blk_m,
                                                  const int* __restrict__ nblk,
                                                  const int* __restrict__ tok_id,
                                                  const float* __restrict__ tok_w,
                                                  float* __restrict__ out) {
    const int b = blockIdx.x / NB2;
    if (b >= *nblk) return;
    const int e  = blk_e[b];
    const int m0 = blk_m[b];
    const int cnt = counts[e];
    const int n0  = (blockIdx.x % NB2) * BN;   // over D
    const int seg = offs[e];
    const int tid = threadIdx.x;

    __shared__ __align__(16) unsigned short As[BM * 64];   // 32 KB
    __shared__ __align__(16) unsigned short Bs[BN * 64];   // 8 KB
    __shared__ int ids[BM];
    __shared__ float wts[BM];

    {
        int rc = min(m0 + tid, cnt - 1);
        ids[tid] = tok_id[seg + rc];
        wts[tid] = tok_w[seg + rc];
    }

    const int lane = tid & 63, wave = tid >> 6;
    const int lr = lane >> 3, lc = lane & 7;
    const int quad = lane >> 4, l16 = lane & 15;

    const unsigned short* ap[8];
#pragma unroll
    for (int j = 0; j < 8; ++j) {
        int rl = wave * 64 + j * 8 + lr;
        ap[j] = hbuf + (size_t)(seg + min(m0 + rl, cnt - 1)) * HH + (lc ^ (rl & 7)) * 8;
    }
    const unsigned short* bp[2];
#pragma unroll
    for (int j = 0; j < 2; ++j) {
        int rl = wave * 16 + j * 8 + lr;
        bp[j] = W2b + ((size_t)e * DD + n0 + rl) * HH + (lc ^ (rl & 7)) * 8;
    }

    floatx4 acc[4][4];
#pragma unroll
    for (int i = 0; i < 4; ++i)
#pragma unroll
        for (int j = 0; j < 4; ++j) acc[i][j] = (floatx4)(0.f);

    for (int k0 = 0; k0 < HH; k0 += BK) {
#pragma unroll
        for (int j = 0; j < 8; ++j)
            gld16(ap[j] + k0, &As[(wave * 64 + j * 8) * 64]);
#pragma unroll
        for (int j = 0; j < 2; ++j)
            gld16(bp[j] + k0, &Bs[(wave * 16 + j * 8) * 64]);
        __syncthreads();
#pragma unroll
        for (int kk = 0; kk < 2; ++kk) {
            bf16x8 a[4], b[4];
#pragma unroll
            for (int mf = 0; mf < 4; ++mf) {
                int r = wave * 64 + mf * 16 + l16;
                int s = (quad + kk * 4) ^ (r & 7);
                a[mf] = *(const bf16x8*)&As[r * 64 + s * 8];
            }
#pragma unroll
            for (int nf = 0; nf < 4; ++nf) {
                int r = nf * 16 + l16;
                int s = (quad + kk * 4) ^ (r & 7);
                b[nf] = *(const bf16x8*)&Bs[r * 64 + s * 8];
            }
#pragma unroll
            for (int mf = 0; mf < 4; ++mf)
#pragma unroll
                for (int nf = 0; nf < 4; ++nf)
                    acc[mf][nf] = __builtin_amdgcn_mfma_f32_16x16x32_bf16(a[mf], b[nf], acc[mf][nf], 0, 0, 0);
        }
        __syncthreads();
    }
#pragma unroll
    for (int mf = 0; mf < 4; ++mf)
#pragma unroll
        for (int reg = 0; reg < 4; ++reg) {
            int m = wave * 64 + mf * 16 + quad * 4 + reg;
            if (m0 + m < cnt) {
                int token = ids[m];
                float w = wts[m];
                float* orow = out + (size_t)token * DD + n0;
#pragma unroll
                for (int nf = 0; nf < 4; ++nf)
                    atomicAdd(orow + nf * 16 + l16, w * acc[mf][nf][reg]);
            }
        }
}

extern "C" void kernel_launch(void* const* d_in, const int* in_sizes, int n_in,
                              void* d_out, int out_size, void* d_ws, size_t ws_size,
                              hipStream_t stream) {
    const float* x  = (const float*)d_in[0];
    const float* Wg = (const float*)d_in[1];
    const float* W1 = (const float*)d_in[2];
    const float* W3 = (const float*)d_in[3];
    const float* W2 = (const float*)d_in[4];
    float* out = (float*)d_out;

    int*   counts = (int*)d_ws;
    int*   cursor = counts + 8;
    int*   offs   = cursor + 8;
    int*   blk_e  = offs + 8;
    int*   blk_m  = blk_e + MAXBLK;
    int*   nblk   = blk_m + MAXBLK;
    int*   topk_i = nblk + 8;   // keep alignment slack
    float* topk_w = (float*)(topk_i + 2 * TT);
    int*   tok_id = (int*)(topk_w + 2 * TT);
    float* tok_w  = (float*)(tok_id + 2 * TT);
    unsigned short* hbuf = (unsigned short*)(tok_w + 2 * TT);     // 2T x H bf16
    unsigned short* Xb   = hbuf + (size_t)2 * TT * HH;            // T x D bf16
    unsigned short* W1b  = Xb + (size_t)TT * DD;                  // E x H x D bf16
    unsigned short* W3b  = W1b + (size_t)EE * HH * DD;
    unsigned short* W2b  = W3b + (size_t)EE * HH * DD;            // E x D x H bf16
    // total ws use ~178.4 MB

    const int nW8 = EE * HH * DD / 8;   // 2883584
    const int nX8 = TT * DD / 8;        // 1048576

    k_init<<<1, 64, 0, stream>>>(counts, cursor);
    k_cvt<<<(nX8 + 255) / 256, 256, 0, stream>>>(x, Xb, nX8);
    k_cvt<<<(nW8 + 255) / 256, 256, 0, stream>>>(W1, W1b, nW8);
    k_cvt<<<(nW8 + 255) / 256, 256, 0, stream>>>(W3, W3b, nW8);
    k_cvt<<<(nW8 + 255) / 256, 256, 0, stream>>>(W2, W2b, nW8);
    k_gate<<<TT, 256, 0, stream>>>(x, Wg, topk_i, topk_w, counts);
    k_scan<<<1, 64, 0, stream>>>(counts, offs, blk_e, blk_m, nblk);
    k_compact<<<TT / 256, 256, 0, stream>>>(topk_i, topk_w, offs, cursor, tok_id, tok_w);
    k_resid<<<(TT * DD / 4) / 256, 256, 0, stream>>>(x, out);
    k_gemm1<<<MAXBLK * NB1, 256, 0, stream>>>(Xb, W1b, W3b, counts, offs,
                                              blk_e, blk_m, nblk, tok_id, hbuf);
    k_gemm2<<<MAXBLK * NB2, 256, 0, stream>>>(hbuf, W2b, counts, offs,
                                              blk_e, blk_m, nblk, tok_id, tok_w, out);
}